// Round 14
// baseline (37.527 us; speedup 1.0000x reference)
//
#include <hip/hip_runtime.h>
#include <math.h>

#define HH 4
#define DD 64
#define BS 32

typedef __attribute__((ext_vector_type(8))) short bf16x8;
typedef __attribute__((ext_vector_type(4))) float f32x4;
#define MFMA16(a,b,c) __builtin_amdgcn_mfma_f32_16x16x32_bf16(a,b,c,0,0,0)

__device__ __forceinline__ float silu_f(float x) { return x / (1.0f + __expf(-x)); }
__device__ __forceinline__ unsigned short f2bf(float f) {
    unsigned u = __float_as_uint(f);
    return (unsigned short)((u + 0x7fffu + ((u >> 16) & 1u)) >> 16);
}

// Kernel A: per (c,h), 4 waves. Means (f32) + K A-frags + V^T B-frags + cmeta.
__global__ __launch_bounds__(256) void hstu_prep(
    const float* __restrict__ k, const float* __restrict__ v,
    const int* __restrict__ offsets, int B,
    float* __restrict__ k_cmp, float* __restrict__ v_cmp,
    uint4* __restrict__ kbA, uint4* __restrict__ vbB,
    int4* __restrict__ cmeta) {
    int c = blockIdx.x, h = blockIdx.y;
    int acc = 0, b = -1, jc = 0;
    for (int bb = 0; bb < B; ++bb) {
        int len = offsets[bb + 1] - offsets[bb];
        int nb = (len + BS - 1) >> 5;
        if (b < 0 && c < acc + nb) { b = bb; jc = c - acc; }
        acc += nb;
    }
    int tid = threadIdx.x, rg = tid >> 6, lane = tid & 63;
    if (b < 0) { if (h == 0 && tid == 0) cmeta[c] = make_int4(-1, -1, 0, 0); return; }
    int t0 = offsets[b] + jc * BS;
    int cnt = offsets[b + 1] - t0; if (cnt > BS) cnt = BS;
    if (h == 0 && tid == 0) cmeta[c] = make_int4(b, jc, t0, cnt);

    __shared__ __align__(16) float kf[BS][DD + 1];
    __shared__ __align__(16) float vf[BS][DD + 1];
    __shared__ float redk[4][DD], redv[4][DD];

    #pragma unroll
    for (int it = 0; it < 2; ++it) {
        int fi = tid + it * 256;
        int row = fi >> 4, ch = fi & 15;
        float4 kk = make_float4(0.f, 0.f, 0.f, 0.f), vv = kk;
        if (row < cnt) {
            size_t off = (size_t)(t0 + row) * (HH * DD) + h * DD + ch * 4;
            kk = *(const float4*)(k + off);
            vv = *(const float4*)(v + off);
        }
        kf[row][ch*4+0] = kk.x; kf[row][ch*4+1] = kk.y; kf[row][ch*4+2] = kk.z; kf[row][ch*4+3] = kk.w;
        vf[row][ch*4+0] = vv.x; vf[row][ch*4+1] = vv.y; vf[row][ch*4+2] = vv.z; vf[row][ch*4+3] = vv.w;
    }
    __syncthreads();

    float kp = 0.f, vp = 0.f;
    #pragma unroll
    for (int m = 0; m < 8; ++m) {
        int row = rg * 8 + m;
        kp += kf[row][lane]; vp += vf[row][lane];
    }
    redk[rg][lane] = kp; redv[rg][lane] = vp;
    __syncthreads();

    int l15 = lane & 15, l4 = lane >> 4;
    size_t fb = ((size_t)c * HH + h) * 4;

    if (rg == 0) {
        float inv = 1.0f / (float)cnt;
        float a = (redk[0][lane] + redk[1][lane] + redk[2][lane] + redk[3][lane]) * inv;
        float bb2 = (redv[0][lane] + redv[1][lane] + redv[2][lane] + redv[3][lane]) * inv;
        k_cmp[(size_t)c * (HH * DD) + h * DD + lane] = a;
        v_cmp[(size_t)c * (HH * DD) + h * DD + lane] = bb2;
    } else if (rg == 1) {
        // K A-frags [mt][half]: A[m=row=mt*16+l15][k = half*32 + l4*8 + e]
        #pragma unroll
        for (int mt = 0; mt < 2; ++mt) {
            int row = mt * 16 + l15;
            #pragma unroll
            for (int hf = 0; hf < 2; ++hf) {
                int d0 = hf * 32 + l4 * 8;
                unsigned w0 = (unsigned)f2bf(kf[row][d0+0]) | ((unsigned)f2bf(kf[row][d0+1]) << 16);
                unsigned w1 = (unsigned)f2bf(kf[row][d0+2]) | ((unsigned)f2bf(kf[row][d0+3]) << 16);
                unsigned w2 = (unsigned)f2bf(kf[row][d0+4]) | ((unsigned)f2bf(kf[row][d0+5]) << 16);
                unsigned w3 = (unsigned)f2bf(kf[row][d0+6]) | ((unsigned)f2bf(kf[row][d0+7]) << 16);
                uint4 o = {w0, w1, w2, w3};
                kbA[(fb + mt * 2 + hf) * 64 + lane] = o;
            }
        }
    } else if (rg == 2) {
        // V B-frags [dt]: B[k=krow=l4*8+e][n=d=dt*16+l15] = V[krow][d]
        #pragma unroll
        for (int dt = 0; dt < 4; ++dt) {
            int d = dt * 16 + l15;
            int kr = l4 * 8;
            unsigned w0 = (unsigned)f2bf(vf[kr+0][d]) | ((unsigned)f2bf(vf[kr+1][d]) << 16);
            unsigned w1 = (unsigned)f2bf(vf[kr+2][d]) | ((unsigned)f2bf(vf[kr+3][d]) << 16);
            unsigned w2 = (unsigned)f2bf(vf[kr+4][d]) | ((unsigned)f2bf(vf[kr+5][d]) << 16);
            unsigned w3 = (unsigned)f2bf(vf[kr+6][d]) | ((unsigned)f2bf(vf[kr+7][d]) << 16);
            uint4 o = {w0, w1, w2, w3};
            vbB[(fb + dt) * 64 + lane] = o;
        }
    }
}

// Kernel B: WG = (c,h), 4 waves. Phase1: per-token scores/top4/o_cmp (R10-validated).
// Phase2: jj-strided MFMA loop, C-operand accumulation (R13-validated). No atomics.
__global__ __launch_bounds__(256) void hstu_fused(
    const float* __restrict__ q,
    const float* __restrict__ g_cmp, const float* __restrict__ g_slc,
    const int* __restrict__ offsets, int B,
    const float* __restrict__ k_cmp, const float* __restrict__ v_cmp,
    const uint4* __restrict__ kbA, const uint4* __restrict__ vbB,
    const int4* __restrict__ cmeta,
    float* __restrict__ o_cmp, float* __restrict__ o_slc) {
    int c = blockIdx.x, h = blockIdx.y;
    int4 meta = cmeta[c];
    int jc = meta.y;
    if (jc < 0) return;
    int t0_blk = meta.z, cnt = meta.w;
    int base_cmp = c - jc;
    int nc = jc + 1;

    __shared__ __align__(16) float4 qls[BS * 17];          // 8704 B
    __shared__ __align__(16) float4 kcl[16 * 16];          // 4 KB, swizzled
    __shared__ __align__(16) float4 vcl[16 * 16];          // 4 KB
    __shared__ __align__(16) unsigned short plds[4][BS * BS]; // 8 KB
    __shared__ __align__(16) float red[4][BS][DD];         // 32 KB
    __shared__ __align__(16) float s_scr[4][16];
    __shared__ __align__(16) float p_scr[4][16];
    __shared__ unsigned selmask_lds[BS];

    int tid = threadIdx.x;
    for (int idx = tid; idx < BS * 16; idx += 256) {
        int row = idx >> 4, ch = idx & 15;
        float4 z4 = make_float4(0.f, 0.f, 0.f, 0.f);
        qls[row * 17 + ch] = (row < cnt)
            ? *(const float4*)(q + (size_t)(t0_blk + row) * (HH * DD) + h * DD + ch * 4) : z4;
    }
    for (int idx = tid; idx < nc * 16; idx += 256) {
        int j = idx >> 4, i = idx & 15;
        size_t g = (size_t)(base_cmp + j) * (HH * DD) + h * DD + i * 4;
        int d = j * 16 + (i ^ (j & 7));
        kcl[d] = *(const float4*)(k_cmp + g);
        vcl[d] = *(const float4*)(v_cmp + g);
    }
    if (tid < BS) selmask_lds[tid] = 0;
    __syncthreads();

    int w = tid >> 6, lane = tid & 63;
    int l15 = lane & 15, l4 = lane >> 4;

    // ---- phase 1 (R10-validated): per-token cmp scores, top-4 -> selmask, o_cmp ----
    {
        int j16 = lane >> 2, g4 = lane & 3;
        int c4 = lane >> 4, d4 = lane & 15;
        for (int m = 0; m < 8; ++m) {
            int tok = w + m * 4;
            if (tok >= cnt) continue;              // wave-uniform
            int t = t0_blk + tok;
            int jclp = (j16 < nc) ? j16 : nc - 1;
            float pp = 0.f;
            #pragma unroll
            for (int cc2 = 0; cc2 < 4; ++cc2) {
                float4 qv = qls[tok * 17 + g4 * 4 + cc2];
                float4 kk = kcl[jclp * 16 + ((g4 * 4 + cc2) ^ (jclp & 7))];
                pp += qv.x * kk.x + qv.y * kk.y + qv.z * kk.z + qv.w * kk.w;
            }
            pp += __shfl_xor(pp, 1);
            pp += __shfl_xor(pp, 2);
            float s_sc = pp * 0.125f;
            float p_sc = (j16 < nc) ? silu_f(s_sc) : 0.f;
            if (g4 == 0) { s_scr[w][j16] = s_sc; p_scr[w][j16] = p_sc; }
            __builtin_amdgcn_wave_barrier();
            float sc_[16], pc_[16];
            #pragma unroll
            for (int x = 0; x < 4; ++x) {
                float4 sd = ((const float4*)s_scr[w])[x];
                float4 pd = ((const float4*)p_scr[w])[x];
                sc_[4*x] = sd.x; sc_[4*x+1] = sd.y; sc_[4*x+2] = sd.z; sc_[4*x+3] = sd.w;
                pc_[4*x] = pd.x; pc_[4*x+1] = pd.y; pc_[4*x+2] = pd.z; pc_[4*x+3] = pd.w;
            }
            float s_own = sc_[j16];
            int rank = 0;
            #pragma unroll
            for (int kx = 0; kx < 16; ++kx) {
                bool beats = (kx < nc) && ((sc_[kx] > s_own) || (sc_[kx] == s_own && kx < j16));
                rank += beats ? 1 : 0;
            }
            bool mine = (g4 == 0) && (j16 < nc) && (rank < 4);
            unsigned long long msk = __ballot(mine);
            unsigned selm = 0;
            #pragma unroll
            for (int jj2 = 0; jj2 < 16; ++jj2)
                selm |= ((unsigned)((msk >> (4 * jj2)) & 1ull)) << jj2;
            if (lane == 0) selmask_lds[tok] = selm;
            // o_cmp
            float4 facc = make_float4(0.f, 0.f, 0.f, 0.f);
            #pragma unroll
            for (int m2 = 0; m2 < 4; ++m2) {
                int jj = m2 * 4 + c4;
                int jjc = (jj < nc) ? jj : nc - 1;
                float4 vv = vcl[jjc * 16 + (d4 ^ (jjc & 7))];
                float pj = pc_[jj];
                facc.x += pj * vv.x; facc.y += pj * vv.y;
                facc.z += pj * vv.z; facc.w += pj * vv.w;
            }
            facc.x += __shfl_xor(facc.x, 16); facc.x += __shfl_xor(facc.x, 32);
            facc.y += __shfl_xor(facc.y, 16); facc.y += __shfl_xor(facc.y, 32);
            facc.z += __shfl_xor(facc.z, 16); facc.z += __shfl_xor(facc.z, 32);
            facc.w += __shfl_xor(facc.w, 16); facc.w += __shfl_xor(facc.w, 32);
            if (c4 == 0) {
                float gc = g_cmp[(size_t)t * HH + h];
                float4 o = make_float4(facc.x * gc, facc.y * gc, facc.z * gc, facc.w * gc);
                *(float4*)(o_cmp + ((size_t)t * HH + h) * DD + d4 * 4) = o;
            }
        }
    }
    __syncthreads();   // selmask visible to all waves

    // ---- Q^T B-frags from LDS (R10-validated formulas) ----
    bf16x8 qb[2][2];
    #pragma unroll
    for (int nt = 0; nt < 2; ++nt) {
        int tokl = nt * 16 + l15;
        #pragma unroll
        for (int ks2 = 0; ks2 < 2; ++ks2) {
            int d0 = ks2 * 32 + l4 * 8;
            float4 f0 = qls[tokl * 17 + (d0 >> 2)];
            float4 f1 = qls[tokl * 17 + (d0 >> 2) + 1];
            bf16x8 a;
            a[0] = (short)f2bf(f0.x); a[1] = (short)f2bf(f0.y);
            a[2] = (short)f2bf(f0.z); a[3] = (short)f2bf(f0.w);
            a[4] = (short)f2bf(f1.x); a[5] = (short)f2bf(f1.y);
            a[6] = (short)f2bf(f1.z); a[7] = (short)f2bf(f1.w);
            qb[nt][ks2] = a;
        }
    }

    unsigned sm_l = (lane < BS) ? selmask_lds[lane] : 0u;
    unsigned sm_n0 = __shfl(sm_l, l15);
    unsigned sm_n1 = __shfl(sm_l, 16 + l15);

    f32x4 z = {0.f, 0.f, 0.f, 0.f};
    f32x4 oacc[2][4];
    #pragma unroll
    for (int tt = 0; tt < 2; ++tt)
        #pragma unroll
        for (int dt = 0; dt < 4; ++dt) oacc[tt][dt] = z;

    // ---- phase 2 (R13-validated): jj-strided MFMA loop ----
    int jcb = jc * BS;
    for (int jj = w; jj <= jc; jj += 4) {
        if (__ballot((sm_l >> jj) & 1u) == 0ull) continue;
        size_t kfb = ((size_t)(base_cmp + jj) * HH + h) * 4;
        uint4 ka00 = kbA[(kfb + 0) * 64 + lane], ka01 = kbA[(kfb + 1) * 64 + lane];
        uint4 ka10 = kbA[(kfb + 2) * 64 + lane], ka11 = kbA[(kfb + 3) * 64 + lane];
        uint4 vb0 = vbB[(kfb + 0) * 64 + lane], vb1 = vbB[(kfb + 1) * 64 + lane];
        uint4 vb2 = vbB[(kfb + 2) * 64 + lane], vb3 = vbB[(kfb + 3) * 64 + lane];

        f32x4 sq[2][2];
        sq[0][0] = MFMA16(*(bf16x8*)&ka00, qb[0][0], z);
        sq[0][0] = MFMA16(*(bf16x8*)&ka01, qb[0][1], sq[0][0]);
        sq[0][1] = MFMA16(*(bf16x8*)&ka00, qb[1][0], z);
        sq[0][1] = MFMA16(*(bf16x8*)&ka01, qb[1][1], sq[0][1]);
        sq[1][0] = MFMA16(*(bf16x8*)&ka10, qb[0][0], z);
        sq[1][0] = MFMA16(*(bf16x8*)&ka11, qb[0][1], sq[1][0]);
        sq[1][1] = MFMA16(*(bf16x8*)&ka10, qb[1][0], z);
        sq[1][1] = MFMA16(*(bf16x8*)&ka11, qb[1][1], sq[1][1]);

        int jjb = jj * BS;
        #pragma unroll
        for (int mt = 0; mt < 2; ++mt) {
            #pragma unroll
            for (int nt = 0; nt < 2; ++nt) {
                int tokl = nt * 16 + l15;
                unsigned sm = nt ? sm_n1 : sm_n0;
                bool selb = (sm >> jj) & 1u;
                #pragma unroll
                for (int i = 0; i < 4; ++i) {
                    int krl = mt * 16 + l4 * 4 + i;
                    bool mk = selb && (jjb + krl <= jcb + tokl);
                    float ps = mk ? silu_f(sq[mt][nt][i] * 0.125f) : 0.f;
                    plds[w][tokl * BS + (((krl >> 3) ^ ((tokl >> 1) & 3)) << 3) + (krl & 7)] = f2bf(ps);
                }
            }
        }
        __builtin_amdgcn_wave_barrier();
        #pragma unroll
        for (int tt = 0; tt < 2; ++tt) {
            int tokl = tt * 16 + l15;
            uint4 pu = *(const uint4*)&plds[w][tokl * BS + ((l4 ^ ((tokl >> 1) & 3)) << 3)];
            bf16x8 pa = *(bf16x8*)&pu;
            oacc[tt][0] = MFMA16(pa, *(bf16x8*)&vb0, oacc[tt][0]);
            oacc[tt][1] = MFMA16(pa, *(bf16x8*)&vb1, oacc[tt][1]);
            oacc[tt][2] = MFMA16(pa, *(bf16x8*)&vb2, oacc[tt][2]);
            oacc[tt][3] = MFMA16(pa, *(bf16x8*)&vb3, oacc[tt][3]);
        }
        __builtin_amdgcn_wave_barrier();
    }

    // ---- epilogue (R13-validated): 4-way LDS reduce + coalesced store ----
    #pragma unroll
    for (int tt = 0; tt < 2; ++tt)
        #pragma unroll
        for (int dt = 0; dt < 4; ++dt)
            #pragma unroll
            for (int i = 0; i < 4; ++i)
                red[w][tt * 16 + l4 * 4 + i][dt * 16 + l15] = oacc[tt][dt][i];
    __syncthreads();
    #pragma unroll
    for (int it = 0; it < 2; ++it) {
        int job = tid + it * 256;
        int tok = job >> 4, ch = job & 15;
        if (tok < cnt) {
            float4 a0 = *(const float4*)&red[0][tok][ch * 4];
            float4 a1 = *(const float4*)&red[1][tok][ch * 4];
            float4 a2 = *(const float4*)&red[2][tok][ch * 4];
            float4 a3 = *(const float4*)&red[3][tok][ch * 4];
            float gs = g_slc[(size_t)(t0_blk + tok) * HH + h];
            float4 o = make_float4((a0.x + a1.x + a2.x + a3.x) * gs,
                                   (a0.y + a1.y + a2.y + a3.y) * gs,
                                   (a0.z + a1.z + a2.z + a3.z) * gs,
                                   (a0.w + a1.w + a2.w + a3.w) * gs);
            *(float4*)(o_slc + ((size_t)(t0_blk + tok) * HH + h) * DD + ch * 4) = o;
        }
    }
}

extern "C" void kernel_launch(void* const* d_in, const int* in_sizes, int n_in,
                              void* d_out, int out_size, void* d_ws, size_t ws_size,
                              hipStream_t stream) {
    const float* q     = (const float*)d_in[0];
    const float* k     = (const float*)d_in[1];
    const float* v     = (const float*)d_in[2];
    const float* g_cmp = (const float*)d_in[3];
    const float* g_slc = (const float*)d_in[4];
    const int*   offs  = (const int*)d_in[5];

    int T = in_sizes[0] / (HH * DD);
    int B = in_sizes[5] - 1;
    int maxC = (T + BS - 1) / BS + B;

    char* w = (char*)d_ws;
    uint4* kbA = (uint4*)w;  w += (size_t)maxC * HH * 4 * 64 * sizeof(uint4);
    uint4* vbB = (uint4*)w;  w += (size_t)maxC * HH * 4 * 64 * sizeof(uint4);
    int4*  cmeta = (int4*)w; w += (size_t)maxC * sizeof(int4);
    float* k_cmp = (float*)w; w += (size_t)maxC * HH * DD * sizeof(float);
    float* v_cmp = (float*)w; w += (size_t)maxC * HH * DD * sizeof(float);

    float* o_cmp = (float*)d_out;
    float* o_slc = (float*)d_out + (size_t)T * HH * DD;

    hipLaunchKernelGGL(hstu_prep, dim3(maxC, HH), dim3(256), 0, stream,
                       k, v, offs, B, k_cmp, v_cmp, kbA, vbB, cmeta);
    hipLaunchKernelGGL(hstu_fused, dim3(maxC, HH), dim3(256), 0, stream,
                       q, g_cmp, g_slc, offs, B, k_cmp, v_cmp, kbA, vbB, cmeta, o_cmp, o_slc);
}

// Round 15
// 28.721 us; speedup vs baseline: 1.3066x; 1.3066x over previous
//
#include <hip/hip_runtime.h>
#include <math.h>

#define HH 4
#define DD 64
#define BS 32

typedef __attribute__((ext_vector_type(8))) short bf16x8;
typedef __attribute__((ext_vector_type(4))) float f32x4;
#define MFMA16(a,b,c) __builtin_amdgcn_mfma_f32_16x16x32_bf16(a,b,c,0,0,0)

__device__ __forceinline__ float silu_f(float x) { return x / (1.0f + __expf(-x)); }
__device__ __forceinline__ unsigned short f2bf(float f) {
    unsigned u = __float_as_uint(f);
    return (unsigned short)((u + 0x7fffu + ((u >> 16) & 1u)) >> 16);
}

// Kernel A: per (c,h), 4 waves. Means (f32) + frag-packed bf16 tiles + cmeta. (R12/R13, validated)
__global__ __launch_bounds__(256) void hstu_prep(
    const float* __restrict__ q, const float* __restrict__ k, const float* __restrict__ v,
    const int* __restrict__ offsets, int B,
    float* __restrict__ k_cmp, float* __restrict__ v_cmp,
    uint4* __restrict__ kbA, uint4* __restrict__ qbB, uint4* __restrict__ vbB,
    int4* __restrict__ cmeta) {
    int c = blockIdx.x, h = blockIdx.y;
    int acc = 0, b = -1, jc = 0;
    for (int bb = 0; bb < B; ++bb) {
        int len = offsets[bb + 1] - offsets[bb];
        int nb = (len + BS - 1) >> 5;
        if (b < 0 && c < acc + nb) { b = bb; jc = c - acc; }
        acc += nb;
    }
    int tid = threadIdx.x, rg = tid >> 6, lane = tid & 63;
    if (b < 0) { if (h == 0 && tid == 0) cmeta[c] = make_int4(-1, -1, 0, 0); return; }
    int t0 = offsets[b] + jc * BS;
    int cnt = offsets[b + 1] - t0; if (cnt > BS) cnt = BS;
    if (h == 0 && tid == 0) cmeta[c] = make_int4(b, jc, t0, cnt);

    __shared__ __align__(16) float kf[BS][DD + 1];
    __shared__ __align__(16) float vf[BS][DD + 1];
    __shared__ __align__(16) unsigned short q16[BS][DD];
    __shared__ float redk[4][DD], redv[4][DD];

    #pragma unroll
    for (int it = 0; it < 2; ++it) {
        int fi = tid + it * 256;
        int row = fi >> 4, ch = fi & 15;
        float4 kk = make_float4(0.f, 0.f, 0.f, 0.f), vv = kk, qq = kk;
        if (row < cnt) {
            size_t off = (size_t)(t0 + row) * (HH * DD) + h * DD + ch * 4;
            kk = *(const float4*)(k + off);
            vv = *(const float4*)(v + off);
            qq = *(const float4*)(q + off);
        }
        kf[row][ch*4+0] = kk.x; kf[row][ch*4+1] = kk.y; kf[row][ch*4+2] = kk.z; kf[row][ch*4+3] = kk.w;
        vf[row][ch*4+0] = vv.x; vf[row][ch*4+1] = vv.y; vf[row][ch*4+2] = vv.z; vf[row][ch*4+3] = vv.w;
        q16[row][ch*4+0] = f2bf(qq.x); q16[row][ch*4+1] = f2bf(qq.y);
        q16[row][ch*4+2] = f2bf(qq.z); q16[row][ch*4+3] = f2bf(qq.w);
    }
    __syncthreads();

    float kp = 0.f, vp = 0.f;
    #pragma unroll
    for (int m = 0; m < 8; ++m) {
        int row = rg * 8 + m;
        kp += kf[row][lane]; vp += vf[row][lane];
    }
    redk[rg][lane] = kp; redv[rg][lane] = vp;
    __syncthreads();

    int l15 = lane & 15, l4 = lane >> 4;
    size_t fb = ((size_t)c * HH + h) * 4;

    if (rg == 0) {
        float inv = 1.0f / (float)cnt;
        float a = (redk[0][lane] + redk[1][lane] + redk[2][lane] + redk[3][lane]) * inv;
        float bb2 = (redv[0][lane] + redv[1][lane] + redv[2][lane] + redv[3][lane]) * inv;
        k_cmp[(size_t)c * (HH * DD) + h * DD + lane] = a;
        v_cmp[(size_t)c * (HH * DD) + h * DD + lane] = bb2;
    } else if (rg == 1) {
        #pragma unroll
        for (int mt = 0; mt < 2; ++mt) {
            int row = mt * 16 + l15;
            #pragma unroll
            for (int hf = 0; hf < 2; ++hf) {
                int d0 = hf * 32 + l4 * 8;
                unsigned w0 = (unsigned)f2bf(kf[row][d0+0]) | ((unsigned)f2bf(kf[row][d0+1]) << 16);
                unsigned w1 = (unsigned)f2bf(kf[row][d0+2]) | ((unsigned)f2bf(kf[row][d0+3]) << 16);
                unsigned w2 = (unsigned)f2bf(kf[row][d0+4]) | ((unsigned)f2bf(kf[row][d0+5]) << 16);
                unsigned w3 = (unsigned)f2bf(kf[row][d0+6]) | ((unsigned)f2bf(kf[row][d0+7]) << 16);
                uint4 o = {w0, w1, w2, w3};
                kbA[(fb + mt * 2 + hf) * 64 + lane] = o;
            }
        }
    } else if (rg == 2) {
        #pragma unroll
        for (int nt = 0; nt < 2; ++nt) {
            int tok = nt * 16 + l15;
            #pragma unroll
            for (int ks2 = 0; ks2 < 2; ++ks2) {
                int d0 = ks2 * 32 + l4 * 8;
                qbB[(fb + nt * 2 + ks2) * 64 + lane] = *(const uint4*)&q16[tok][d0];
            }
        }
    } else {
        #pragma unroll
        for (int dt = 0; dt < 4; ++dt) {
            int d = dt * 16 + l15;
            int kr = l4 * 8;
            unsigned w0 = (unsigned)f2bf(vf[kr+0][d]) | ((unsigned)f2bf(vf[kr+1][d]) << 16);
            unsigned w1 = (unsigned)f2bf(vf[kr+2][d]) | ((unsigned)f2bf(vf[kr+3][d]) << 16);
            unsigned w2 = (unsigned)f2bf(vf[kr+4][d]) | ((unsigned)f2bf(vf[kr+5][d]) << 16);
            unsigned w3 = (unsigned)f2bf(vf[kr+6][d]) | ((unsigned)f2bf(vf[kr+7][d]) << 16);
            uint4 o = {w0, w1, w2, w3};
            vbB[(fb + dt) * 64 + lane] = o;
        }
    }
}

// Kernel B1: per-token scores + top-4 -> selmask + o_cmp. grid=T, 4 waves=heads. (validated)
__global__ __launch_bounds__(256) void hstu_sel(
    const float* __restrict__ q, const float* __restrict__ g_cmp,
    const int* __restrict__ offsets, int B,
    const float* __restrict__ k_cmp, const float* __restrict__ v_cmp,
    float* __restrict__ o_cmp, unsigned short* __restrict__ selmask) {
    int t = blockIdx.x;
    int h = threadIdx.x >> 6;
    int lane = threadIdx.x & 63;
    __shared__ __align__(16) float s_lds[HH][16];
    __shared__ __align__(16) float p_lds[HH][16];

    int b = 0;
    while (b + 1 < B && t >= offsets[b + 1]) ++b;
    int p = t - offsets[b];
    int q_blk = p >> 5;
    int base_cmp = 0, totC = 0;
    for (int bb = 0; bb < B; ++bb) {
        int nb = (offsets[bb + 1] - offsets[bb] + BS - 1) >> 5;
        if (bb < b) base_cmp += nb;
        totC += nb;
    }

    int d4 = lane & 15, c4 = lane >> 4;
    float4 qf = *(const float4*)(q + ((size_t)t * HH + h) * DD + d4 * 4);
    float sc_own[4], pc_own[4];
    #pragma unroll
    for (int m = 0; m < 4; ++m) {
        int j = m * 4 + c4;
        int ci = base_cmp + j; if (ci > totC - 1) ci = totC - 1;
        float4 kk = *(const float4*)(k_cmp + (size_t)ci * (HH * DD) + h * DD + d4 * 4);
        float pp = qf.x * kk.x + qf.y * kk.y + qf.z * kk.z + qf.w * kk.w;
        pp += __shfl_xor(pp, 1);
        pp += __shfl_xor(pp, 2);
        pp += __shfl_xor(pp, 4);
        pp += __shfl_xor(pp, 8);
        sc_own[m] = pp * 0.125f;
        pc_own[m] = (j <= q_blk) ? silu_f(sc_own[m]) : 0.f;
    }
    if (d4 == 0) {
        #pragma unroll
        for (int m = 0; m < 4; ++m) {
            s_lds[h][m * 4 + c4] = sc_own[m];
            p_lds[h][m * 4 + c4] = pc_own[m];
        }
    }
    __builtin_amdgcn_wave_barrier();

    float sc_[16], pc_[16];
    #pragma unroll
    for (int x = 0; x < 4; ++x) {
        float4 sd = ((const float4*)s_lds[h])[x];
        float4 pd = ((const float4*)p_lds[h])[x];
        sc_[x*4+0] = sd.x; sc_[x*4+1] = sd.y; sc_[x*4+2] = sd.z; sc_[x*4+3] = sd.w;
        pc_[x*4+0] = pd.x; pc_[x*4+1] = pd.y; pc_[x*4+2] = pd.z; pc_[x*4+3] = pd.w;
    }

    int j_own = lane >> 2;
    float s_own = sc_[j_own];
    int rank = 0;
    #pragma unroll
    for (int kk = 0; kk < 16; ++kk) {
        bool beats = (kk <= q_blk) && ((sc_[kk] > s_own) || (sc_[kk] == s_own && kk < j_own));
        rank += beats ? 1 : 0;
    }
    bool mine = ((lane & 3) == 0) && (j_own <= q_blk) && (rank < 4);
    unsigned long long msk = __ballot(mine);
    unsigned selm = 0;
    #pragma unroll
    for (int jj2 = 0; jj2 < 16; ++jj2)
        selm |= ((unsigned)((msk >> (4 * jj2)) & 1ull)) << jj2;
    if (lane == 0) selmask[(size_t)t * HH + h] = (unsigned short)selm;

    float4 facc = make_float4(0.f, 0.f, 0.f, 0.f);
    #pragma unroll
    for (int m = 0; m < 4; ++m) {
        int j = m * 4 + c4;
        int ci = base_cmp + j; if (ci > totC - 1) ci = totC - 1;
        float4 vv = *(const float4*)(v_cmp + (size_t)ci * (HH * DD) + h * DD + d4 * 4);
        float pj = pc_[j];
        facc.x += pj * vv.x; facc.y += pj * vv.y; facc.z += pj * vv.z; facc.w += pj * vv.w;
    }
    facc.x += __shfl_xor(facc.x, 16); facc.x += __shfl_xor(facc.x, 32);
    facc.y += __shfl_xor(facc.y, 16); facc.y += __shfl_xor(facc.y, 32);
    facc.z += __shfl_xor(facc.z, 16); facc.z += __shfl_xor(facc.z, 32);
    facc.w += __shfl_xor(facc.w, 16); facc.w += __shfl_xor(facc.w, 32);
    if (c4 == 0) {
        float gc = g_cmp[(size_t)t * HH + h];
        float4 o = make_float4(facc.x * gc, facc.y * gc, facc.z * gc, facc.w * gc);
        *(float4*)(o_cmp + ((size_t)t * HH + h) * DD + d4 * 4) = o;
    }
}

// Kernel B2: WG = (c,h), 4 waves. Wave r handles K-blocks jj = r, r+4, ...; PV accumulates
// across jj in C-operand. LDS 4-way reduce + coalesced store. No atomics. (R13, validated)
__global__ __launch_bounds__(256) void hstu_slc_mfma(
    const float* __restrict__ g_slc,
    const uint4* __restrict__ kbA, const uint4* __restrict__ qbB, const uint4* __restrict__ vbB,
    const int4* __restrict__ cmeta, const unsigned short* __restrict__ selmask,
    float* __restrict__ o_slc) {
    int c = blockIdx.x, h = blockIdx.y;
    int4 meta = cmeta[c];
    int jc = meta.y;
    if (jc < 0) return;
    int t0_blk = meta.z, cnt = meta.w;
    int base_c = c - jc;

    int tid = threadIdx.x, w = tid >> 6, lane = tid & 63;
    int l15 = lane & 15, l4 = lane >> 4;

    __shared__ __align__(16) unsigned short plds[4][BS * BS];  // 8 KB, wave-private
    __shared__ __align__(16) float red[4][BS][DD];             // 32 KB

    unsigned sm_l = 0;
    if (lane < BS && lane < cnt)
        sm_l = (unsigned)selmask[(size_t)(t0_blk + lane) * HH + h];
    unsigned sm_n0 = __shfl(sm_l, l15);
    unsigned sm_n1 = __shfl(sm_l, 16 + l15);

    size_t qfb = ((size_t)c * HH + h) * 4;
    uint4 qb0 = qbB[(qfb + 0) * 64 + lane], qb1 = qbB[(qfb + 1) * 64 + lane];
    uint4 qb2 = qbB[(qfb + 2) * 64 + lane], qb3 = qbB[(qfb + 3) * 64 + lane];

    f32x4 z = {0.f, 0.f, 0.f, 0.f};
    f32x4 oacc[2][4];
    #pragma unroll
    for (int tt = 0; tt < 2; ++tt)
        #pragma unroll
        for (int dt = 0; dt < 4; ++dt) oacc[tt][dt] = z;

    int jcb = jc * BS;
    for (int jj = w; jj <= jc; jj += 4) {
        if (__ballot((sm_l >> jj) & 1u) == 0ull) continue;   // wave-uniform skip
        size_t kfb = ((size_t)(base_c + jj) * HH + h) * 4;
        uint4 ka00 = kbA[(kfb + 0) * 64 + lane], ka01 = kbA[(kfb + 1) * 64 + lane];
        uint4 ka10 = kbA[(kfb + 2) * 64 + lane], ka11 = kbA[(kfb + 3) * 64 + lane];
        uint4 vb0 = vbB[(kfb + 0) * 64 + lane], vb1 = vbB[(kfb + 1) * 64 + lane];
        uint4 vb2 = vbB[(kfb + 2) * 64 + lane], vb3 = vbB[(kfb + 3) * 64 + lane];

        f32x4 sq[2][2];
        sq[0][0] = MFMA16(*(bf16x8*)&ka00, *(bf16x8*)&qb0, z);
        sq[0][0] = MFMA16(*(bf16x8*)&ka01, *(bf16x8*)&qb1, sq[0][0]);
        sq[0][1] = MFMA16(*(bf16x8*)&ka00, *(bf16x8*)&qb2, z);
        sq[0][1] = MFMA16(*(bf16x8*)&ka01, *(bf16x8*)&qb3, sq[0][1]);
        sq[1][0] = MFMA16(*(bf16x8*)&ka10, *(bf16x8*)&qb0, z);
        sq[1][0] = MFMA16(*(bf16x8*)&ka11, *(bf16x8*)&qb1, sq[1][0]);
        sq[1][1] = MFMA16(*(bf16x8*)&ka10, *(bf16x8*)&qb2, z);
        sq[1][1] = MFMA16(*(bf16x8*)&ka11, *(bf16x8*)&qb3, sq[1][1]);

        int jjb = jj * BS;
        #pragma unroll
        for (int mt = 0; mt < 2; ++mt) {
            #pragma unroll
            for (int nt = 0; nt < 2; ++nt) {
                int tokl = nt * 16 + l15;
                unsigned sm = nt ? sm_n1 : sm_n0;
                bool selb = (sm >> jj) & 1u;
                #pragma unroll
                for (int i = 0; i < 4; ++i) {
                    int krl = mt * 16 + l4 * 4 + i;
                    bool mk = selb && (jjb + krl <= jcb + tokl);
                    float ps = mk ? silu_f(sq[mt][nt][i] * 0.125f) : 0.f;
                    plds[w][tokl * BS + (((krl >> 3) ^ ((tokl >> 1) & 3)) << 3) + (krl & 7)] = f2bf(ps);
                }
            }
        }
        __builtin_amdgcn_wave_barrier();
        #pragma unroll
        for (int tt = 0; tt < 2; ++tt) {
            int tokl = tt * 16 + l15;
            uint4 pu = *(const uint4*)&plds[w][tokl * BS + ((l4 ^ ((tokl >> 1) & 3)) << 3)];
            bf16x8 pa = *(bf16x8*)&pu;
            oacc[tt][0] = MFMA16(pa, *(bf16x8*)&vb0, oacc[tt][0]);
            oacc[tt][1] = MFMA16(pa, *(bf16x8*)&vb1, oacc[tt][1]);
            oacc[tt][2] = MFMA16(pa, *(bf16x8*)&vb2, oacc[tt][2]);
            oacc[tt][3] = MFMA16(pa, *(bf16x8*)&vb3, oacc[tt][3]);
        }
        __builtin_amdgcn_wave_barrier();
    }

    // dump per-wave partials, reduce 4-way, scale, store coalesced
    #pragma unroll
    for (int tt = 0; tt < 2; ++tt)
        #pragma unroll
        for (int dt = 0; dt < 4; ++dt)
            #pragma unroll
            for (int i = 0; i < 4; ++i)
                red[w][tt * 16 + l4 * 4 + i][dt * 16 + l15] = oacc[tt][dt][i];
    __syncthreads();
    #pragma unroll
    for (int it = 0; it < 2; ++it) {
        int job = tid + it * 256;
        int tok = job >> 4, ch = job & 15;
        if (tok < cnt) {
            float4 a0 = *(const float4*)&red[0][tok][ch * 4];
            float4 a1 = *(const float4*)&red[1][tok][ch * 4];
            float4 a2 = *(const float4*)&red[2][tok][ch * 4];
            float4 a3 = *(const float4*)&red[3][tok][ch * 4];
            float gs = g_slc[(size_t)(t0_blk + tok) * HH + h];
            float4 o = make_float4((a0.x + a1.x + a2.x + a3.x) * gs,
                                   (a0.y + a1.y + a2.y + a3.y) * gs,
                                   (a0.z + a1.z + a2.z + a3.z) * gs,
                                   (a0.w + a1.w + a2.w + a3.w) * gs);
            *(float4*)(o_slc + ((size_t)(t0_blk + tok) * HH + h) * DD + ch * 4) = o;
        }
    }
}

extern "C" void kernel_launch(void* const* d_in, const int* in_sizes, int n_in,
                              void* d_out, int out_size, void* d_ws, size_t ws_size,
                              hipStream_t stream) {
    const float* q     = (const float*)d_in[0];
    const float* k     = (const float*)d_in[1];
    const float* v     = (const float*)d_in[2];
    const float* g_cmp = (const float*)d_in[3];
    const float* g_slc = (const float*)d_in[4];
    const int*   offs  = (const int*)d_in[5];

    int T = in_sizes[0] / (HH * DD);
    int B = in_sizes[5] - 1;
    int maxC = (T + BS - 1) / BS + B;

    char* w = (char*)d_ws;
    uint4* kbA = (uint4*)w;  w += (size_t)maxC * HH * 4 * 64 * sizeof(uint4);
    uint4* qbB = (uint4*)w;  w += (size_t)maxC * HH * 4 * 64 * sizeof(uint4);
    uint4* vbB = (uint4*)w;  w += (size_t)maxC * HH * 4 * 64 * sizeof(uint4);
    int4*  cmeta = (int4*)w; w += (size_t)maxC * sizeof(int4);
    float* k_cmp = (float*)w; w += (size_t)maxC * HH * DD * sizeof(float);
    float* v_cmp = (float*)w; w += (size_t)maxC * HH * DD * sizeof(float);
    unsigned short* selmask = (unsigned short*)w;

    float* o_cmp = (float*)d_out;
    float* o_slc = (float*)d_out + (size_t)T * HH * DD;

    hipLaunchKernelGGL(hstu_prep, dim3(maxC, HH), dim3(256), 0, stream,
                       q, k, v, offs, B, k_cmp, v_cmp, kbA, qbB, vbB, cmeta);
    hipLaunchKernelGGL(hstu_sel, dim3(T), dim3(256), 0, stream,
                       q, g_cmp, offs, B, k_cmp, v_cmp, o_cmp, selmask);
    hipLaunchKernelGGL(hstu_slc_mfma, dim3(maxC, HH), dim3(256), 0, stream,
                       g_slc, kbA, qbB, vbB, cmeta, selmask, o_slc);
}